// Round 1
// baseline (62.191 us; speedup 1.0000x reference)
//
#include <hip/hip_runtime.h>
#include <math.h>

#define NA 256
#define NR 8
#define NBASIS 10
#define OUT_PER 603

__device__ __forceinline__ float pairTerm(const float* A, const float* B, int l) {
    if (l == 0) return A[0] * B[0];
    if (l == 1) return A[1] * B[1] + A[2] * B[2] + A[3] * B[3];
    return 1.5f * (A[4] * B[4] + A[5] * B[5] + A[6] * B[6])
         + 3.0f * (A[7] * B[7] + A[8] * B[8] + A[9] * B[9])
         - 0.5f * A[0] * B[0];
}

__global__ __launch_bounds__(256) void desc_kernel(
    const float* __restrict__ pos,
    const float* __restrict__ mag,
    const float* __restrict__ cell,
    float* __restrict__ out)
{
    const int i = blockIdx.x;
    const int tid = threadIdx.x;

    __shared__ float sF[NA][NR];        // radial basis per candidate j
    __shared__ float sB[NA][NBASIS];    // angular basis per candidate j
    __shared__ float sW[NA][5];         // mx,my,mz,s_ij,u_j
    __shared__ unsigned char sValid[NA];
    __shared__ float sM[5][NR][NBASIS]; // moments, kinds {1,mx,my,mz,s}
    __shared__ float sMu[NR];           // sum f*u  (rho_m2)
    __shared__ float sD[3][NR][NR];     // diag corrections: rr, mm(u), imm(s^2)

    const float CUT = 4.5f;
    const float spacing = CUT / (float)(NR - 1);
    const float beta = 1.0f / (spacing * spacing);
    const float PI_F = 3.14159265358979323846f;

    // --- cell and its inverse (redundant per thread; 9 scalar loads broadcast) ---
    float c00 = cell[0], c01 = cell[1], c02 = cell[2];
    float c10 = cell[3], c11 = cell[4], c12 = cell[5];
    float c20 = cell[6], c21 = cell[7], c22 = cell[8];
    float det = c00 * (c11 * c22 - c12 * c21)
              - c01 * (c10 * c22 - c12 * c20)
              + c02 * (c10 * c21 - c11 * c20);
    float rdet = 1.0f / det;
    float i00 =  (c11 * c22 - c12 * c21) * rdet;
    float i01 =  (c02 * c21 - c01 * c22) * rdet;
    float i02 =  (c01 * c12 - c02 * c11) * rdet;
    float i10 =  (c12 * c20 - c10 * c22) * rdet;
    float i11 =  (c00 * c22 - c02 * c20) * rdet;
    float i12 =  (c02 * c10 - c00 * c12) * rdet;
    float i20 =  (c10 * c21 - c11 * c20) * rdet;
    float i21 =  (c01 * c20 - c00 * c21) * rdet;
    float i22 =  (c00 * c11 - c01 * c10) * rdet;

    float px = pos[3 * i], py = pos[3 * i + 1], pz = pos[3 * i + 2];
    float mix = mag[3 * i], miy = mag[3 * i + 1], miz = mag[3 * i + 2];

    // --- phase 1: per-pair quantities ---
    {
        int j = tid;
        float dx = pos[3 * j] - px, dy = pos[3 * j + 1] - py, dz = pos[3 * j + 2] - pz;
        // frac = disp @ inv_cell (row-vector * matrix)
        float fx = dx * i00 + dy * i10 + dz * i20;
        float fy = dx * i01 + dy * i11 + dz * i21;
        float fz = dx * i02 + dy * i12 + dz * i22;
        fx -= rintf(fx); fy -= rintf(fy); fz -= rintf(fz);
        // r = frac @ cell
        float rx = fx * c00 + fy * c10 + fz * c20;
        float ry = fx * c01 + fy * c11 + fz * c21;
        float rz = fx * c02 + fy * c12 + fz * c22;
        float d2 = rx * rx + ry * ry + rz * rz;
        float d = sqrtf(d2);
        bool valid = (j != i) && (d < CUT);
        sValid[j] = valid ? 1 : 0;
        if (valid) {
            float fc = 0.5f * (cosf(PI_F * d / CUT) + 1.0f);
            float invd = 1.0f / d;
            float xh = rx * invd, yh = ry * invd, zh = rz * invd;
            #pragma unroll
            for (int a = 0; a < NR; ++a) {
                float diff = d - (float)a * spacing;
                sF[j][a] = __expf(-beta * diff * diff) * fc;
            }
            sB[j][0] = 1.0f;
            sB[j][1] = xh; sB[j][2] = yh; sB[j][3] = zh;
            sB[j][4] = xh * xh; sB[j][5] = yh * yh; sB[j][6] = zh * zh;
            sB[j][7] = xh * yh; sB[j][8] = xh * zh; sB[j][9] = yh * zh;
            float mjx = mag[3 * j], mjy = mag[3 * j + 1], mjz = mag[3 * j + 2];
            float s = mix * mjx + miy * mjy + miz * mjz;
            float u = mjx * mjx + mjy * mjy + mjz * mjz;
            sW[j][0] = mjx; sW[j][1] = mjy; sW[j][2] = mjz;
            sW[j][3] = s;   sW[j][4] = u;
        }
    }
    __syncthreads();

    // --- phase 2: moments (400 + 8) ---
    for (int m = tid; m < 408; m += 256) {
        float acc = 0.0f;
        if (m < 400) {
            int kind = m / 80;
            int rest = m % 80;
            int a = rest / NBASIS;
            int q = rest % NBASIS;
            for (int n = 0; n < NA; ++n) {
                if (!sValid[n]) continue;
                float w = (kind == 0) ? 1.0f : sW[n][kind - 1];
                acc += sF[n][a] * sB[n][q] * w;
            }
            sM[kind][a][q] = acc;
        } else {
            int a = m - 400;
            for (int n = 0; n < NA; ++n) {
                if (!sValid[n]) continue;
                acc += sF[n][a] * sW[n][4];
            }
            sMu[a] = acc;
        }
    }

    // --- phase 3: diagonal (j==k) corrections, 3*64 ---
    for (int m = tid; m < 192; m += 256) {
        int kind = m / 64;
        int ab = m % 64;
        int a = ab / NR, b = ab % NR;
        float acc = 0.0f;
        for (int n = 0; n < NA; ++n) {
            if (!sValid[n]) continue;
            float w;
            if (kind == 0) w = 1.0f;
            else if (kind == 1) w = sW[n][4];          // u_j
            else { float s = sW[n][3]; w = s * s; }    // s_ij^2
            acc += sF[n][a] * sF[n][b] * w;
        }
        sD[kind][a][b] = acc;
    }
    __syncthreads();

    // --- phase 4: outputs (603 per atom) ---
    for (int o = tid; o < OUT_PER; o += 256) {
        float val;
        if (o < 3) {
            float u = mix * mix + miy * miy + miz * miz;
            float un = u / (2.2f * 2.2f);
            val = (o == 0) ? un : ((o == 1) ? un * un : un * un * un);
        } else if (o < 11) {
            val = sM[0][o - 3][0];                      // rho_r
        } else if (o < 203) {
            int idx = o - 11;
            int a = idx / 24, b = (idx / 3) % 8, l = idx % 3;
            val = pairTerm(sM[0][a], sM[0][b], l) - sD[0][a][b];
        } else if (o < 211) {
            val = sMu[o - 203];                         // rho_m2
        } else if (o < 219) {
            val = sM[4][o - 211][0];                    // rho_im
        } else if (o < 411) {
            int idx = o - 219;
            int a = idx / 24, b = (idx / 3) % 8, l = idx % 3;
            val = pairTerm(sM[1][a], sM[1][b], l)
                + pairTerm(sM[2][a], sM[2][b], l)
                + pairTerm(sM[3][a], sM[3][b], l)
                - sD[1][a][b];
        } else {
            int idx = o - 411;
            int a = idx / 24, b = (idx / 3) % 8, l = idx % 3;
            val = pairTerm(sM[4][a], sM[4][b], l) - sD[2][a][b];
        }
        out[i * OUT_PER + o] = val;
    }
}

extern "C" void kernel_launch(void* const* d_in, const int* in_sizes, int n_in,
                              void* d_out, int out_size, void* d_ws, size_t ws_size,
                              hipStream_t stream) {
    const float* pos  = (const float*)d_in[0];
    const float* mag  = (const float*)d_in[1];
    const float* cell = (const float*)d_in[2];
    float* out = (float*)d_out;
    desc_kernel<<<NA, 256, 0, stream>>>(pos, mag, cell, out);
}

// Round 2
// 13.466 us; speedup vs baseline: 4.6183x; 4.6183x over previous
//
#include <hip/hip_runtime.h>
#include <math.h>

#define NA 256
#define NR 8
#define NBASIS 10
#define OUT_PER 603

__device__ __forceinline__ float pairTerm(const float* A, const float* B, int l) {
    if (l == 0) return A[0] * B[0];
    if (l == 1) return A[1] * B[1] + A[2] * B[2] + A[3] * B[3];
    return 1.5f * (A[4] * B[4] + A[5] * B[5] + A[6] * B[6])
         + 3.0f * (A[7] * B[7] + A[8] * B[8] + A[9] * B[9])
         - 0.5f * A[0] * B[0];
}

__global__ __launch_bounds__(256) void desc_kernel(
    const float* __restrict__ pos,
    const float* __restrict__ mag,
    const float* __restrict__ cell,
    float* __restrict__ out)
{
    const int i = blockIdx.x;
    const int tid = threadIdx.x;
    const int wid = tid >> 6;
    const int lane = tid & 63;

    // compacted per-neighbor arrays (slot-indexed, only [0,total) used)
    __shared__ float sF[NA][NR];        // radial basis
    __shared__ float sB[NA][NBASIS];    // angular basis
    __shared__ float sW[NA][5];         // mx,my,mz,s_ij,u_j
    __shared__ int   sWaveCnt[4];
    __shared__ float sM[5][NR][NBASIS]; // moments, kinds {1,mx,my,mz,s}
    __shared__ float sMu[NR];           // sum f*u  (rho_m2)
    __shared__ float sD[3][NR][NR];     // diag corrections: rr, mm(u), imm(s^2)

    const float CUT = 4.5f;
    const float spacing = CUT / (float)(NR - 1);
    const float beta = 1.0f / (spacing * spacing);
    const float PI_F = 3.14159265358979323846f;

    // --- cell and its inverse (broadcast scalar loads) ---
    float c00 = cell[0], c01 = cell[1], c02 = cell[2];
    float c10 = cell[3], c11 = cell[4], c12 = cell[5];
    float c20 = cell[6], c21 = cell[7], c22 = cell[8];
    float det = c00 * (c11 * c22 - c12 * c21)
              - c01 * (c10 * c22 - c12 * c20)
              + c02 * (c10 * c21 - c11 * c20);
    float rdet = 1.0f / det;
    float i00 =  (c11 * c22 - c12 * c21) * rdet;
    float i01 =  (c02 * c21 - c01 * c22) * rdet;
    float i02 =  (c01 * c12 - c02 * c11) * rdet;
    float i10 =  (c12 * c20 - c10 * c22) * rdet;
    float i11 =  (c00 * c22 - c02 * c20) * rdet;
    float i12 =  (c02 * c10 - c00 * c12) * rdet;
    float i20 =  (c10 * c21 - c11 * c20) * rdet;
    float i21 =  (c01 * c20 - c00 * c21) * rdet;
    float i22 =  (c00 * c11 - c01 * c10) * rdet;

    float px = pos[3 * i], py = pos[3 * i + 1], pz = pos[3 * i + 2];
    float mix = mag[3 * i], miy = mag[3 * i + 1], miz = mag[3 * i + 2];

    // --- phase 1: per-pair quantities + wave-ballot compaction ---
    int j = tid;
    float dx = pos[3 * j] - px, dy = pos[3 * j + 1] - py, dz = pos[3 * j + 2] - pz;
    float fx = dx * i00 + dy * i10 + dz * i20;
    float fy = dx * i01 + dy * i11 + dz * i21;
    float fz = dx * i02 + dy * i12 + dz * i22;
    fx -= rintf(fx); fy -= rintf(fy); fz -= rintf(fz);
    float rx = fx * c00 + fy * c10 + fz * c20;
    float ry = fx * c01 + fy * c11 + fz * c21;
    float rz = fx * c02 + fy * c12 + fz * c22;
    float d2 = rx * rx + ry * ry + rz * rz;
    float d = sqrtf(d2);
    bool valid = (j != i) && (d < CUT);

    unsigned long long mask = __ballot(valid);
    int pre = __popcll(mask & ((1ull << lane) - 1ull));
    if (lane == 0) sWaveCnt[wid] = __popcll(mask);
    __syncthreads();
    int base = 0;
    #pragma unroll
    for (int w = 0; w < 4; ++w) base += (w < wid) ? sWaveCnt[w] : 0;
    const int total = sWaveCnt[0] + sWaveCnt[1] + sWaveCnt[2] + sWaveCnt[3];

    if (valid) {
        int slot = base + pre;
        float fc = 0.5f * (cosf(PI_F * d / CUT) + 1.0f);
        float invd = 1.0f / d;
        float xh = rx * invd, yh = ry * invd, zh = rz * invd;
        #pragma unroll
        for (int a = 0; a < NR; ++a) {
            float diff = d - (float)a * spacing;
            sF[slot][a] = __expf(-beta * diff * diff) * fc;
        }
        sB[slot][0] = 1.0f;
        sB[slot][1] = xh; sB[slot][2] = yh; sB[slot][3] = zh;
        sB[slot][4] = xh * xh; sB[slot][5] = yh * yh; sB[slot][6] = zh * zh;
        sB[slot][7] = xh * yh; sB[slot][8] = xh * zh; sB[slot][9] = yh * zh;
        float mjx = mag[3 * j], mjy = mag[3 * j + 1], mjz = mag[3 * j + 2];
        float s = mix * mjx + miy * mjy + miz * mjz;
        float u = mjx * mjx + mjy * mjy + mjz * mjz;
        sW[slot][0] = mjx; sW[slot][1] = mjy; sW[slot][2] = mjz;
        sW[slot][3] = s;   sW[slot][4] = u;
    }
    __syncthreads();

    // --- phase 2: moments (400 + 8) over compacted list ---
    for (int m = tid; m < 408; m += 256) {
        float acc = 0.0f;
        if (m < 400) {
            int kind = m / 80;
            int rest = m % 80;
            int a = rest / NBASIS;
            int q = rest % NBASIS;
            for (int n = 0; n < total; ++n) {
                float w = (kind == 0) ? 1.0f : sW[n][kind - 1];
                acc += sF[n][a] * sB[n][q] * w;
            }
            sM[kind][a][q] = acc;
        } else {
            int a = m - 400;
            for (int n = 0; n < total; ++n)
                acc += sF[n][a] * sW[n][4];
            sMu[a] = acc;
        }
    }

    // --- phase 3: diagonal (j==k) corrections, 3*64 ---
    for (int m = tid; m < 192; m += 256) {
        int kind = m / 64;
        int ab = m % 64;
        int a = ab / NR, b = ab % NR;
        float acc = 0.0f;
        for (int n = 0; n < total; ++n) {
            float w;
            if (kind == 0) w = 1.0f;
            else if (kind == 1) w = sW[n][4];          // u_j
            else { float s = sW[n][3]; w = s * s; }    // s_ij^2
            acc += sF[n][a] * sF[n][b] * w;
        }
        sD[kind][a][b] = acc;
    }
    __syncthreads();

    // --- phase 4: outputs (603 per atom) ---
    for (int o = tid; o < OUT_PER; o += 256) {
        float val;
        if (o < 3) {
            float u = mix * mix + miy * miy + miz * miz;
            float un = u / (2.2f * 2.2f);
            val = (o == 0) ? un : ((o == 1) ? un * un : un * un * un);
        } else if (o < 11) {
            val = sM[0][o - 3][0];                      // rho_r
        } else if (o < 203) {
            int idx = o - 11;
            int a = idx / 24, b = (idx / 3) % 8, l = idx % 3;
            val = pairTerm(sM[0][a], sM[0][b], l) - sD[0][a][b];
        } else if (o < 211) {
            val = sMu[o - 203];                         // rho_m2
        } else if (o < 219) {
            val = sM[4][o - 211][0];                    // rho_im
        } else if (o < 411) {
            int idx = o - 219;
            int a = idx / 24, b = (idx / 3) % 8, l = idx % 3;
            val = pairTerm(sM[1][a], sM[1][b], l)
                + pairTerm(sM[2][a], sM[2][b], l)
                + pairTerm(sM[3][a], sM[3][b], l)
                - sD[1][a][b];
        } else {
            int idx = o - 411;
            int a = idx / 24, b = (idx / 3) % 8, l = idx % 3;
            val = pairTerm(sM[4][a], sM[4][b], l) - sD[2][a][b];
        }
        out[i * OUT_PER + o] = val;
    }
}

extern "C" void kernel_launch(void* const* d_in, const int* in_sizes, int n_in,
                              void* d_out, int out_size, void* d_ws, size_t ws_size,
                              hipStream_t stream) {
    const float* pos  = (const float*)d_in[0];
    const float* mag  = (const float*)d_in[1];
    const float* cell = (const float*)d_in[2];
    float* out = (float*)d_out;
    desc_kernel<<<NA, 256, 0, stream>>>(pos, mag, cell, out);
}

// Round 3
// 12.187 us; speedup vs baseline: 5.1031x; 1.1050x over previous
//
#include <hip/hip_runtime.h>
#include <math.h>

#define NA 256
#define NR 8
#define NBASIS 10
#define OUT_PER 603
#define PAD 4

__device__ __forceinline__ float pairTerm(const float* A, const float* B, int l) {
    if (l == 0) return A[0] * B[0];
    if (l == 1) return A[1] * B[1] + A[2] * B[2] + A[3] * B[3];
    return 1.5f * (A[4] * B[4] + A[5] * B[5] + A[6] * B[6])
         + 3.0f * (A[7] * B[7] + A[8] * B[8] + A[9] * B[9])
         - 0.5f * A[0] * B[0];
}

__global__ __launch_bounds__(256) void desc_kernel(
    const float* __restrict__ pos,
    const float* __restrict__ mag,
    const float* __restrict__ cell,
    float* __restrict__ out)
{
    const int i = blockIdx.x;
    const int tid = threadIdx.x;
    const int wid = tid >> 6;
    const int lane = tid & 63;

    // compacted per-neighbor arrays; rows [total, total+PAD) zero-filled
    __shared__ float sF[NA + PAD][NR];
    __shared__ float sB[NA + PAD][NBASIS];
    __shared__ float sW[NA + PAD][5];
    __shared__ int   sWaveCnt[4];
    __shared__ float sM[5][NR][NBASIS];
    __shared__ float sMu[NR];
    __shared__ float sD[3][NR][NR];

    const float CUT = 4.5f;
    const float spacing = CUT / (float)(NR - 1);
    const float beta = 1.0f / (spacing * spacing);
    const float PI_F = 3.14159265358979323846f;

    // --- cell inverse (broadcast scalar loads) ---
    float c00 = cell[0], c01 = cell[1], c02 = cell[2];
    float c10 = cell[3], c11 = cell[4], c12 = cell[5];
    float c20 = cell[6], c21 = cell[7], c22 = cell[8];
    float det = c00 * (c11 * c22 - c12 * c21)
              - c01 * (c10 * c22 - c12 * c20)
              + c02 * (c10 * c21 - c11 * c20);
    float rdet = 1.0f / det;
    float i00 =  (c11 * c22 - c12 * c21) * rdet;
    float i01 =  (c02 * c21 - c01 * c22) * rdet;
    float i02 =  (c01 * c12 - c02 * c11) * rdet;
    float i10 =  (c12 * c20 - c10 * c22) * rdet;
    float i11 =  (c00 * c22 - c02 * c20) * rdet;
    float i12 =  (c02 * c10 - c00 * c12) * rdet;
    float i20 =  (c10 * c21 - c11 * c20) * rdet;
    float i21 =  (c01 * c20 - c00 * c21) * rdet;
    float i22 =  (c00 * c11 - c01 * c10) * rdet;

    float px = pos[3 * i], py = pos[3 * i + 1], pz = pos[3 * i + 2];
    float mix = mag[3 * i], miy = mag[3 * i + 1], miz = mag[3 * i + 2];

    // --- phase 1: per-pair quantities + wave-ballot compaction ---
    int j = tid;
    float dx = pos[3 * j] - px, dy = pos[3 * j + 1] - py, dz = pos[3 * j + 2] - pz;
    float fx = dx * i00 + dy * i10 + dz * i20;
    float fy = dx * i01 + dy * i11 + dz * i21;
    float fz = dx * i02 + dy * i12 + dz * i22;
    fx -= rintf(fx); fy -= rintf(fy); fz -= rintf(fz);
    float rx = fx * c00 + fy * c10 + fz * c20;
    float ry = fx * c01 + fy * c11 + fz * c21;
    float rz = fx * c02 + fy * c12 + fz * c22;
    float d2 = rx * rx + ry * ry + rz * rz;
    float d = sqrtf(d2);
    bool valid = (j != i) && (d < CUT);

    unsigned long long mask = __ballot(valid);
    int pre = __popcll(mask & ((1ull << lane) - 1ull));
    if (lane == 0) sWaveCnt[wid] = __popcll(mask);
    __syncthreads();
    int base = 0;
    #pragma unroll
    for (int w = 0; w < 4; ++w) base += (w < wid) ? sWaveCnt[w] : 0;
    const int total = sWaveCnt[0] + sWaveCnt[1] + sWaveCnt[2] + sWaveCnt[3];

    if (valid) {
        int slot = base + pre;
        float fc = 0.5f * (__cosf(PI_F * d / CUT) + 1.0f);
        float invd = 1.0f / d;
        float xh = rx * invd, yh = ry * invd, zh = rz * invd;
        #pragma unroll
        for (int a = 0; a < NR; ++a) {
            float diff = d - (float)a * spacing;
            sF[slot][a] = __expf(-beta * diff * diff) * fc;
        }
        sB[slot][0] = 1.0f;
        sB[slot][1] = xh; sB[slot][2] = yh; sB[slot][3] = zh;
        sB[slot][4] = xh * xh; sB[slot][5] = yh * yh; sB[slot][6] = zh * zh;
        sB[slot][7] = xh * yh; sB[slot][8] = xh * zh; sB[slot][9] = yh * zh;
        float mjx = mag[3 * j], mjy = mag[3 * j + 1], mjz = mag[3 * j + 2];
        float s = mix * mjx + miy * mjy + miz * mjz;
        float u = mjx * mjx + mjy * mjy + mjz * mjz;
        sW[slot][0] = mjx; sW[slot][1] = mjy; sW[slot][2] = mjz;
        sW[slot][3] = s;   sW[slot][4] = u;
    }
    // zero-fill PAD rows past `total` so the unroll-4 loops can over-read
    if (tid < PAD) {
        int r = total + tid;
        #pragma unroll
        for (int a = 0; a < NR; ++a) sF[r][a] = 0.0f;
        #pragma unroll
        for (int q = 0; q < NBASIS; ++q) sB[r][q] = 0.0f;
        #pragma unroll
        for (int w = 0; w < 5; ++w) sW[r][w] = 0.0f;
    }
    __syncthreads();

    // --- phase 2: moments (400 + 8), unroll-4 with independent accumulators ---
    for (int m = tid; m < 408; m += 256) {
        float a0 = 0.0f, a1 = 0.0f, a2 = 0.0f, a3 = 0.0f;
        if (m < 400) {
            int kind = m / 80;
            int rest = m % 80;
            int a = rest / NBASIS;
            int q = rest % NBASIS;
            for (int n = 0; n < total; n += 4) {
                float w0 = (kind == 0) ? 1.0f : sW[n + 0][kind - 1];
                float w1 = (kind == 0) ? 1.0f : sW[n + 1][kind - 1];
                float w2 = (kind == 0) ? 1.0f : sW[n + 2][kind - 1];
                float w3 = (kind == 0) ? 1.0f : sW[n + 3][kind - 1];
                a0 += sF[n + 0][a] * sB[n + 0][q] * w0;
                a1 += sF[n + 1][a] * sB[n + 1][q] * w1;
                a2 += sF[n + 2][a] * sB[n + 2][q] * w2;
                a3 += sF[n + 3][a] * sB[n + 3][q] * w3;
            }
            sM[kind][a][q] = (a0 + a1) + (a2 + a3);
        } else {
            int a = m - 400;
            for (int n = 0; n < total; n += 4) {
                a0 += sF[n + 0][a] * sW[n + 0][4];
                a1 += sF[n + 1][a] * sW[n + 1][4];
                a2 += sF[n + 2][a] * sW[n + 2][4];
                a3 += sF[n + 3][a] * sW[n + 3][4];
            }
            sMu[a] = (a0 + a1) + (a2 + a3);
        }
    }

    // --- phase 3: diagonal (j==k) corrections, unroll-4 ---
    for (int m = tid; m < 192; m += 256) {
        int kind = m / 64;
        int ab = m % 64;
        int a = ab / NR, b = ab % NR;
        float a0 = 0.0f, a1 = 0.0f, a2 = 0.0f, a3 = 0.0f;
        for (int n = 0; n < total; n += 4) {
            float w0, w1, w2, w3;
            if (kind == 0) { w0 = w1 = w2 = w3 = 1.0f; }
            else if (kind == 1) {
                w0 = sW[n + 0][4]; w1 = sW[n + 1][4];
                w2 = sW[n + 2][4]; w3 = sW[n + 3][4];
            } else {
                float s0 = sW[n + 0][3], s1 = sW[n + 1][3];
                float s2 = sW[n + 2][3], s3 = sW[n + 3][3];
                w0 = s0 * s0; w1 = s1 * s1; w2 = s2 * s2; w3 = s3 * s3;
            }
            a0 += sF[n + 0][a] * sF[n + 0][b] * w0;
            a1 += sF[n + 1][a] * sF[n + 1][b] * w1;
            a2 += sF[n + 2][a] * sF[n + 2][b] * w2;
            a3 += sF[n + 3][a] * sF[n + 3][b] * w3;
        }
        sD[kind][a][b] = (a0 + a1) + (a2 + a3);
    }
    __syncthreads();

    // --- phase 4: outputs (603 per atom) ---
    for (int o = tid; o < OUT_PER; o += 256) {
        float val;
        if (o < 3) {
            float u = mix * mix + miy * miy + miz * miz;
            float un = u / (2.2f * 2.2f);
            val = (o == 0) ? un : ((o == 1) ? un * un : un * un * un);
        } else if (o < 11) {
            val = sM[0][o - 3][0];                      // rho_r
        } else if (o < 203) {
            int idx = o - 11;
            int a = idx / 24, b = (idx / 3) % 8, l = idx % 3;
            val = pairTerm(sM[0][a], sM[0][b], l) - sD[0][a][b];
        } else if (o < 211) {
            val = sMu[o - 203];                         // rho_m2
        } else if (o < 219) {
            val = sM[4][o - 211][0];                    // rho_im
        } else if (o < 411) {
            int idx = o - 219;
            int a = idx / 24, b = (idx / 3) % 8, l = idx % 3;
            val = pairTerm(sM[1][a], sM[1][b], l)
                + pairTerm(sM[2][a], sM[2][b], l)
                + pairTerm(sM[3][a], sM[3][b], l)
                - sD[1][a][b];
        } else {
            int idx = o - 411;
            int a = idx / 24, b = (idx / 3) % 8, l = idx % 3;
            val = pairTerm(sM[4][a], sM[4][b], l) - sD[2][a][b];
        }
        out[i * OUT_PER + o] = val;
    }
}

extern "C" void kernel_launch(void* const* d_in, const int* in_sizes, int n_in,
                              void* d_out, int out_size, void* d_ws, size_t ws_size,
                              hipStream_t stream) {
    const float* pos  = (const float*)d_in[0];
    const float* mag  = (const float*)d_in[1];
    const float* cell = (const float*)d_in[2];
    float* out = (float*)d_out;
    desc_kernel<<<NA, 256, 0, stream>>>(pos, mag, cell, out);
}

// Round 5
// 10.452 us; speedup vs baseline: 5.9501x; 1.1660x over previous
//
#include <hip/hip_runtime.h>
#include <math.h>

#define NA 256
#define NR 8
#define NBASIS 10
#define OUT_PER 603
#define PAD 4
#define BLK 1024

__device__ __forceinline__ float pairTerm(const float* A, const float* B, int l) {
    if (l == 0) return A[0] * B[0];
    if (l == 1) return A[1] * B[1] + A[2] * B[2] + A[3] * B[3];
    return 1.5f * (A[4] * B[4] + A[5] * B[5] + A[6] * B[6])
         + 3.0f * (A[7] * B[7] + A[8] * B[8] + A[9] * B[9])
         - 0.5f * A[0] * B[0];
}

__global__ __launch_bounds__(BLK) void desc_kernel(
    const float* __restrict__ pos,
    const float* __restrict__ mag,
    const float* __restrict__ cell,
    float* __restrict__ out)
{
    const int i = blockIdx.x;
    const int tid = threadIdx.x;
    const int wid = tid >> 6;    // 0..15
    const int lane = tid & 63;

    __shared__ float sF[NA + PAD][NR];
    __shared__ float sB[NA + PAD][NBASIS];
    __shared__ float sW[NA + PAD][5];
    __shared__ int   sWaveCnt[4];
    __shared__ float sM[5][NR][NBASIS];
    __shared__ float sMu[NR];
    __shared__ float sD[3][NR][NR];

    const float CUT = 4.5f;
    const float spacing = CUT / (float)(NR - 1);
    const float beta = 1.0f / (spacing * spacing);
    const float PI_F = 3.14159265358979323846f;

    float mix = mag[3 * i], miy = mag[3 * i + 1], miz = mag[3 * i + 2];

    // --- phase 1 (waves 0-3 only): per-pair quantities + ballot compaction ---
    bool valid = false;
    float rx = 0.f, ry = 0.f, rz = 0.f, d = 0.f;
    float mjx = 0.f, mjy = 0.f, mjz = 0.f;
    int pre = 0;

    if (tid < NA) {
        int j = tid;
        // issue all global loads up front
        float pjx = pos[3 * j], pjy = pos[3 * j + 1], pjz = pos[3 * j + 2];
        mjx = mag[3 * j]; mjy = mag[3 * j + 1]; mjz = mag[3 * j + 2];
        float px = pos[3 * i], py = pos[3 * i + 1], pz = pos[3 * i + 2];

        float c00 = cell[0], c01 = cell[1], c02 = cell[2];
        float c10 = cell[3], c11 = cell[4], c12 = cell[5];
        float c20 = cell[6], c21 = cell[7], c22 = cell[8];
        float det = c00 * (c11 * c22 - c12 * c21)
                  - c01 * (c10 * c22 - c12 * c20)
                  + c02 * (c10 * c21 - c11 * c20);
        float rdet = 1.0f / det;
        float i00 =  (c11 * c22 - c12 * c21) * rdet;
        float i01 =  (c02 * c21 - c01 * c22) * rdet;
        float i02 =  (c01 * c12 - c02 * c11) * rdet;
        float i10 =  (c12 * c20 - c10 * c22) * rdet;
        float i11 =  (c00 * c22 - c02 * c20) * rdet;
        float i12 =  (c02 * c10 - c00 * c12) * rdet;
        float i20 =  (c10 * c21 - c11 * c20) * rdet;
        float i21 =  (c01 * c20 - c00 * c21) * rdet;
        float i22 =  (c00 * c11 - c01 * c10) * rdet;

        float dx = pjx - px, dy = pjy - py, dz = pjz - pz;
        float fx = dx * i00 + dy * i10 + dz * i20;
        float fy = dx * i01 + dy * i11 + dz * i21;
        float fz = dx * i02 + dy * i12 + dz * i22;
        fx -= rintf(fx); fy -= rintf(fy); fz -= rintf(fz);
        rx = fx * c00 + fy * c10 + fz * c20;
        ry = fx * c01 + fy * c11 + fz * c21;
        rz = fx * c02 + fy * c12 + fz * c22;
        d = sqrtf(rx * rx + ry * ry + rz * rz);
        valid = (j != i) && (d < CUT);

        unsigned long long m64 = __ballot(valid);
        pre = __popcll(m64 & ((1ull << lane) - 1ull));
        if (lane == 0) sWaveCnt[wid] = __popcll(m64);
    }
    __syncthreads();
    const int total = sWaveCnt[0] + sWaveCnt[1] + sWaveCnt[2] + sWaveCnt[3];

    if (tid < NA) {
        int base = 0;
        #pragma unroll
        for (int w = 0; w < 4; ++w) base += (w < wid) ? sWaveCnt[w] : 0;
        if (valid) {
            int slot = base + pre;
            float fc = 0.5f * (__cosf(PI_F * d / CUT) + 1.0f);
            float invd = 1.0f / d;
            float xh = rx * invd, yh = ry * invd, zh = rz * invd;
            #pragma unroll
            for (int a = 0; a < NR; ++a) {
                float diff = d - (float)a * spacing;
                sF[slot][a] = __expf(-beta * diff * diff) * fc;
            }
            sB[slot][0] = 1.0f;
            sB[slot][1] = xh; sB[slot][2] = yh; sB[slot][3] = zh;
            sB[slot][4] = xh * xh; sB[slot][5] = yh * yh; sB[slot][6] = zh * zh;
            sB[slot][7] = xh * yh; sB[slot][8] = xh * zh; sB[slot][9] = yh * zh;
            float s = mix * mjx + miy * mjy + miz * mjz;
            float u = mjx * mjx + mjy * mjy + mjz * mjz;
            sW[slot][0] = mjx; sW[slot][1] = mjy; sW[slot][2] = mjz;
            sW[slot][3] = s;   sW[slot][4] = u;
        }
        if (tid < PAD) {
            int r = total + tid;
            #pragma unroll
            for (int a = 0; a < NR; ++a) sF[r][a] = 0.0f;
            #pragma unroll
            for (int q = 0; q < NBASIS; ++q) sB[r][q] = 0.0f;
            #pragma unroll
            for (int w = 0; w < 5; ++w) sW[r][w] = 0.0f;
        }
    }
    __syncthreads();

    // --- combined phase 2+3: 600 concurrent tasks, one per thread ---
    if (tid < 408) {
        float a0 = 0.0f, a1 = 0.0f, a2 = 0.0f, a3 = 0.0f;
        if (tid < 400) {
            int kind = tid / 80;
            int rest = tid % 80;
            int a = rest / NBASIS;
            int q = rest % NBASIS;
            for (int n = 0; n < total; n += 4) {
                float w0 = (kind == 0) ? 1.0f : sW[n + 0][kind - 1];
                float w1 = (kind == 0) ? 1.0f : sW[n + 1][kind - 1];
                float w2 = (kind == 0) ? 1.0f : sW[n + 2][kind - 1];
                float w3 = (kind == 0) ? 1.0f : sW[n + 3][kind - 1];
                a0 += sF[n + 0][a] * sB[n + 0][q] * w0;
                a1 += sF[n + 1][a] * sB[n + 1][q] * w1;
                a2 += sF[n + 2][a] * sB[n + 2][q] * w2;
                a3 += sF[n + 3][a] * sB[n + 3][q] * w3;
            }
            sM[kind][a][q] = (a0 + a1) + (a2 + a3);
        } else {
            int a = tid - 400;
            for (int n = 0; n < total; n += 4) {
                a0 += sF[n + 0][a] * sW[n + 0][4];
                a1 += sF[n + 1][a] * sW[n + 1][4];
                a2 += sF[n + 2][a] * sW[n + 2][4];
                a3 += sF[n + 3][a] * sW[n + 3][4];
            }
            sMu[a] = (a0 + a1) + (a2 + a3);
        }
    } else if (tid < 600) {
        int m = tid - 408;
        int kind = m / 64;
        int ab = m % 64;
        int a = ab / NR, b = ab % NR;
        float a0 = 0.0f, a1 = 0.0f, a2 = 0.0f, a3 = 0.0f;
        for (int n = 0; n < total; n += 4) {
            float w0, w1, w2, w3;
            if (kind == 0) { w0 = w1 = w2 = w3 = 1.0f; }
            else if (kind == 1) {
                w0 = sW[n + 0][4]; w1 = sW[n + 1][4];
                w2 = sW[n + 2][4]; w3 = sW[n + 3][4];
            } else {
                float s0 = sW[n + 0][3], s1 = sW[n + 1][3];
                float s2 = sW[n + 2][3], s3 = sW[n + 3][3];
                w0 = s0 * s0; w1 = s1 * s1; w2 = s2 * s2; w3 = s3 * s3;
            }
            a0 += sF[n + 0][a] * sF[n + 0][b] * w0;
            a1 += sF[n + 1][a] * sF[n + 1][b] * w1;
            a2 += sF[n + 2][a] * sF[n + 2][b] * w2;
            a3 += sF[n + 3][a] * sF[n + 3][b] * w3;
        }
        sD[kind][a][b] = (a0 + a1) + (a2 + a3);
    }
    __syncthreads();

    // --- phase 4: 603 outputs, one per thread ---
    if (tid < OUT_PER) {
        const int o = tid;
        float val;
        if (o < 3) {
            float u = mix * mix + miy * miy + miz * miz;
            float un = u / (2.2f * 2.2f);
            val = (o == 0) ? un : ((o == 1) ? un * un : un * un * un);
        } else if (o < 11) {
            val = sM[0][o - 3][0];                      // rho_r
        } else if (o < 203) {
            int idx = o - 11;
            int a = idx / 24, b = (idx / 3) % 8, l = idx % 3;
            val = pairTerm(sM[0][a], sM[0][b], l) - sD[0][a][b];
        } else if (o < 211) {
            val = sMu[o - 203];                         // rho_m2
        } else if (o < 219) {
            val = sM[4][o - 211][0];                    // rho_im
        } else if (o < 411) {
            int idx = o - 219;
            int a = idx / 24, b = (idx / 3) % 8, l = idx % 3;
            val = pairTerm(sM[1][a], sM[1][b], l)
                + pairTerm(sM[2][a], sM[2][b], l)
                + pairTerm(sM[3][a], sM[3][b], l)
                - sD[1][a][b];
        } else {
            int idx = o - 411;
            int a = idx / 24, b = (idx / 3) % 8, l = idx % 3;
            val = pairTerm(sM[4][a], sM[4][b], l) - sD[2][a][b];
        }
        out[i * OUT_PER + o] = val;
    }
}

extern "C" void kernel_launch(void* const* d_in, const int* in_sizes, int n_in,
                              void* d_out, int out_size, void* d_ws, size_t ws_size,
                              hipStream_t stream) {
    const float* pos  = (const float*)d_in[0];
    const float* mag  = (const float*)d_in[1];
    const float* cell = (const float*)d_in[2];
    float* out = (float*)d_out;
    desc_kernel<<<NA, BLK, 0, stream>>>(pos, mag, cell, out);
}

// Round 6
// 10.298 us; speedup vs baseline: 6.0393x; 1.0150x over previous
//
#include <hip/hip_runtime.h>
#include <math.h>

#define NA 256
#define NR 8
#define NBASIS 10
#define OUT_PER 603
#define PAD 4
#define BLK 640   // 10 waves: phases 2+3 (600 tasks) and 4 (603 outputs) in one trip

__device__ __forceinline__ float pairTerm(const float* A, const float* B, int l) {
    if (l == 0) return A[0] * B[0];
    if (l == 1) return A[1] * B[1] + A[2] * B[2] + A[3] * B[3];
    return 1.5f * (A[4] * B[4] + A[5] * B[5] + A[6] * B[6])
         + 3.0f * (A[7] * B[7] + A[8] * B[8] + A[9] * B[9])
         - 0.5f * A[0] * B[0];
}

__global__ __launch_bounds__(BLK) void desc_kernel(
    const float* __restrict__ pos,
    const float* __restrict__ mag,
    const float* __restrict__ cell,
    float* __restrict__ out)
{
    const int i = blockIdx.x;
    const int tid = threadIdx.x;
    const int wid = tid >> 6;
    const int lane = tid & 63;

    __shared__ float sF[NA + PAD][NR];
    __shared__ float sB[NA + PAD][NBASIS];
    __shared__ float sW[NA + PAD][5];
    __shared__ int   sWaveCnt[4];
    __shared__ float sM[5][NR][NBASIS];
    __shared__ float sMu[NR];
    __shared__ float sD[3][NR][NR];

    const float CUT = 4.5f;
    const float CUT2 = CUT * CUT;
    const float spacing = CUT / (float)(NR - 1);
    const float beta = 1.0f / (spacing * spacing);
    const float PI_F = 3.14159265358979323846f;

    float mix = mag[3 * i], miy = mag[3 * i + 1], miz = mag[3 * i + 2];

    // --- phase 1 (waves 0-3 only): per-pair quantities + ballot compaction ---
    bool valid = false;
    float rx = 0.f, ry = 0.f, rz = 0.f, d2 = 0.f;
    float mjx = 0.f, mjy = 0.f, mjz = 0.f;
    int pre = 0;

    if (tid < NA) {
        int j = tid;
        float pjx = pos[3 * j], pjy = pos[3 * j + 1], pjz = pos[3 * j + 2];
        mjx = mag[3 * j]; mjy = mag[3 * j + 1]; mjz = mag[3 * j + 2];
        float px = pos[3 * i], py = pos[3 * i + 1], pz = pos[3 * i + 2];

        float c00 = cell[0], c01 = cell[1], c02 = cell[2];
        float c10 = cell[3], c11 = cell[4], c12 = cell[5];
        float c20 = cell[6], c21 = cell[7], c22 = cell[8];
        float det = c00 * (c11 * c22 - c12 * c21)
                  - c01 * (c10 * c22 - c12 * c20)
                  + c02 * (c10 * c21 - c11 * c20);
        float rdet = 1.0f / det;
        float i00 =  (c11 * c22 - c12 * c21) * rdet;
        float i01 =  (c02 * c21 - c01 * c22) * rdet;
        float i02 =  (c01 * c12 - c02 * c11) * rdet;
        float i10 =  (c12 * c20 - c10 * c22) * rdet;
        float i11 =  (c00 * c22 - c02 * c20) * rdet;
        float i12 =  (c02 * c10 - c00 * c12) * rdet;
        float i20 =  (c10 * c21 - c11 * c20) * rdet;
        float i21 =  (c01 * c20 - c00 * c21) * rdet;
        float i22 =  (c00 * c11 - c01 * c10) * rdet;

        float dx = pjx - px, dy = pjy - py, dz = pjz - pz;
        float fx = dx * i00 + dy * i10 + dz * i20;
        float fy = dx * i01 + dy * i11 + dz * i21;
        float fz = dx * i02 + dy * i12 + dz * i22;
        fx -= rintf(fx); fy -= rintf(fy); fz -= rintf(fz);
        rx = fx * c00 + fy * c10 + fz * c20;
        ry = fx * c01 + fy * c11 + fz * c21;
        rz = fx * c02 + fy * c12 + fz * c22;
        d2 = rx * rx + ry * ry + rz * rz;
        valid = (j != i) && (d2 < CUT2);

        unsigned long long m64 = __ballot(valid);
        pre = __popcll(m64 & ((1ull << lane) - 1ull));
        if (lane == 0) sWaveCnt[wid] = __popcll(m64);
    }
    __syncthreads();
    const int total = sWaveCnt[0] + sWaveCnt[1] + sWaveCnt[2] + sWaveCnt[3];

    if (tid < NA) {
        int base = 0;
        #pragma unroll
        for (int w = 0; w < 4; ++w) base += (w < wid) ? sWaveCnt[w] : 0;
        if (valid) {
            int slot = base + pre;
            float invd = rsqrtf(d2);
            float d = d2 * invd;
            float fc = 0.5f * (__cosf(PI_F * d / CUT) + 1.0f);
            float xh = rx * invd, yh = ry * invd, zh = rz * invd;
            #pragma unroll
            for (int a = 0; a < NR; ++a) {
                float diff = d - (float)a * spacing;
                sF[slot][a] = __expf(-beta * diff * diff) * fc;
            }
            sB[slot][0] = 1.0f;
            sB[slot][1] = xh; sB[slot][2] = yh; sB[slot][3] = zh;
            sB[slot][4] = xh * xh; sB[slot][5] = yh * yh; sB[slot][6] = zh * zh;
            sB[slot][7] = xh * yh; sB[slot][8] = xh * zh; sB[slot][9] = yh * zh;
            float s = mix * mjx + miy * mjy + miz * mjz;
            float u = mjx * mjx + mjy * mjy + mjz * mjz;
            sW[slot][0] = mjx; sW[slot][1] = mjy; sW[slot][2] = mjz;
            sW[slot][3] = s;   sW[slot][4] = u;
        }
        if (tid < PAD) {
            int r = total + tid;
            #pragma unroll
            for (int a = 0; a < NR; ++a) sF[r][a] = 0.0f;
            #pragma unroll
            for (int q = 0; q < NBASIS; ++q) sB[r][q] = 0.0f;
            #pragma unroll
            for (int w = 0; w < 5; ++w) sW[r][w] = 0.0f;
        }
    }
    __syncthreads();

    // --- combined phase 2+3: 600 concurrent tasks, one per thread ---
    if (tid < 408) {
        float a0 = 0.0f, a1 = 0.0f, a2 = 0.0f, a3 = 0.0f;
        if (tid < 400) {
            int kind = tid / 80;
            int rest = tid % 80;
            int a = rest / NBASIS;
            int q = rest % NBASIS;
            for (int n = 0; n < total; n += 4) {
                float w0 = (kind == 0) ? 1.0f : sW[n + 0][kind - 1];
                float w1 = (kind == 0) ? 1.0f : sW[n + 1][kind - 1];
                float w2 = (kind == 0) ? 1.0f : sW[n + 2][kind - 1];
                float w3 = (kind == 0) ? 1.0f : sW[n + 3][kind - 1];
                a0 += sF[n + 0][a] * sB[n + 0][q] * w0;
                a1 += sF[n + 1][a] * sB[n + 1][q] * w1;
                a2 += sF[n + 2][a] * sB[n + 2][q] * w2;
                a3 += sF[n + 3][a] * sB[n + 3][q] * w3;
            }
            sM[kind][a][q] = (a0 + a1) + (a2 + a3);
        } else {
            int a = tid - 400;
            for (int n = 0; n < total; n += 4) {
                a0 += sF[n + 0][a] * sW[n + 0][4];
                a1 += sF[n + 1][a] * sW[n + 1][4];
                a2 += sF[n + 2][a] * sW[n + 2][4];
                a3 += sF[n + 3][a] * sW[n + 3][4];
            }
            sMu[a] = (a0 + a1) + (a2 + a3);
        }
    } else if (tid < 600) {
        int m = tid - 408;
        int kind = m / 64;
        int ab = m % 64;
        int a = ab / NR, b = ab % NR;
        float a0 = 0.0f, a1 = 0.0f, a2 = 0.0f, a3 = 0.0f;
        for (int n = 0; n < total; n += 4) {
            float w0, w1, w2, w3;
            if (kind == 0) { w0 = w1 = w2 = w3 = 1.0f; }
            else if (kind == 1) {
                w0 = sW[n + 0][4]; w1 = sW[n + 1][4];
                w2 = sW[n + 2][4]; w3 = sW[n + 3][4];
            } else {
                float s0 = sW[n + 0][3], s1 = sW[n + 1][3];
                float s2 = sW[n + 2][3], s3 = sW[n + 3][3];
                w0 = s0 * s0; w1 = s1 * s1; w2 = s2 * s2; w3 = s3 * s3;
            }
            a0 += sF[n + 0][a] * sF[n + 0][b] * w0;
            a1 += sF[n + 1][a] * sF[n + 1][b] * w1;
            a2 += sF[n + 2][a] * sF[n + 2][b] * w2;
            a3 += sF[n + 3][a] * sF[n + 3][b] * w3;
        }
        sD[kind][a][b] = (a0 + a1) + (a2 + a3);
    }
    __syncthreads();

    // --- phase 4: 603 outputs, one per thread ---
    if (tid < OUT_PER) {
        const int o = tid;
        float val;
        if (o < 3) {
            float u = mix * mix + miy * miy + miz * miz;
            float un = u / (2.2f * 2.2f);
            val = (o == 0) ? un : ((o == 1) ? un * un : un * un * un);
        } else if (o < 11) {
            val = sM[0][o - 3][0];                      // rho_r
        } else if (o < 203) {
            int idx = o - 11;
            int a = idx / 24, b = (idx / 3) % 8, l = idx % 3;
            val = pairTerm(sM[0][a], sM[0][b], l) - sD[0][a][b];
        } else if (o < 211) {
            val = sMu[o - 203];                         // rho_m2
        } else if (o < 219) {
            val = sM[4][o - 211][0];                    // rho_im
        } else if (o < 411) {
            int idx = o - 219;
            int a = idx / 24, b = (idx / 3) % 8, l = idx % 3;
            val = pairTerm(sM[1][a], sM[1][b], l)
                + pairTerm(sM[2][a], sM[2][b], l)
                + pairTerm(sM[3][a], sM[3][b], l)
                - sD[1][a][b];
        } else {
            int idx = o - 411;
            int a = idx / 24, b = (idx / 3) % 8, l = idx % 3;
            val = pairTerm(sM[4][a], sM[4][b], l) - sD[2][a][b];
        }
        out[i * OUT_PER + o] = val;
    }
}

extern "C" void kernel_launch(void* const* d_in, const int* in_sizes, int n_in,
                              void* d_out, int out_size, void* d_ws, size_t ws_size,
                              hipStream_t stream) {
    const float* pos  = (const float*)d_in[0];
    const float* mag  = (const float*)d_in[1];
    const float* cell = (const float*)d_in[2];
    float* out = (float*)d_out;
    desc_kernel<<<NA, BLK, 0, stream>>>(pos, mag, cell, out);
}